// Round 1
// baseline (275.486 us; speedup 1.0000x reference)
//
#include <hip/hip_runtime.h>
#include <math.h>

#define NN    128
#define NN2   16384        // N*N
#define CDIM  256
#define BV    8
#define MM    64
#define RR    128          // M*K pos rows
#define PP    8256         // N*(N+1)/2
#define NBLK  1032         // 66048 / 64 cols per block
#define BPB   129          // blocks per video (8256/64)
#define TEMP  0.1f
#define NEGIOU 0.5f

typedef __attribute__((ext_vector_type(8))) short bf16x8;
typedef __attribute__((ext_vector_type(4))) float f32x4;

static __device__ __forceinline__ unsigned short f2bf(float x) {
    union { float f; unsigned u; } c; c.f = x;
    unsigned r = c.u + 0x7FFFu + ((c.u >> 16) & 1u);   // RNE
    return (unsigned short)(r >> 16);
}

// ---------------- Kernel 1: fused global top-2 per moment + pos features --------
// One block per moment m. Phase A: 256 threads scan the 16384 iou2ds entries
// (upper-tri only), two-stage LDS merge with index tie-break (== jax top_k).
// Phase B: waves 0/1 fetch + l2-normalize the two selected proposal rows with the
// EXACT same per-lane 4-channel + shfl_xor reduction order as the old posfeat
// kernel (bit-identical pos/posFrag).
__global__ __launch_bounds__(256) void pos_kernel(const float* __restrict__ iou2ds,
                                                  const float* __restrict__ vfeat,
                                                  float* __restrict__ pos,
                                                  unsigned short* __restrict__ posFrag) {
    int m = blockIdx.x, tid = threadIdx.x;
    const float* src = iou2ds + (size_t)m * NN2;
    float v1 = -1e30f, v2 = -1e30f;
    int k1 = 0x7fffffff, k2 = 0x7fffffff;
#pragma unroll 4
    for (int i = 0; i < 64; ++i) {
        int k = tid + 256 * i;                    // ascending k per thread
        int rr = k >> 7, cc = k & 127;
        if (cc < rr) continue;                    // upper-triangular mask
        float v = src[k];
        if (v > v1 || (v == v1 && k < k1)) { v2 = v1; k2 = k1; v1 = v; k1 = k; }
        else if (v > v2 || (v == v2 && k < k2)) { v2 = v; k2 = k; }
    }
    __shared__ float sv[512];  __shared__ int sk[512];
    __shared__ float sv2[128]; __shared__ int sk2[128];
    __shared__ int sIdx[2];
    sv[tid * 2] = v1; sv[tid * 2 + 1] = v2;
    sk[tid * 2] = k1; sk[tid * 2 + 1] = k2;
    __syncthreads();
    if (tid < 64) {
        float b1 = -1e30f, b2 = -1e30f; int c1 = 0x7fffffff, c2 = 0x7fffffff;
        for (int t = tid * 8; t < tid * 8 + 8; ++t) {
            float v = sv[t]; int k = sk[t];
            if (v > b1 || (v == b1 && k < c1)) { b2 = b1; c2 = c1; b1 = v; c1 = k; }
            else if (v > b2 || (v == b2 && k < c2)) { b2 = v; c2 = k; }
        }
        sv2[tid * 2] = b1; sv2[tid * 2 + 1] = b2;
        sk2[tid * 2] = c1; sk2[tid * 2 + 1] = c2;
    }
    __syncthreads();
    if (tid == 0) {
        float b1 = -1e30f, b2 = -1e30f; int c1 = 0x7fffffff, c2 = 0x7fffffff;
        for (int t = 0; t < 128; ++t) {
            float v = sv2[t]; int k = sk2[t];
            if (v > b1 || (v == b1 && k < c1)) { b2 = b1; c2 = c1; b1 = v; c1 = k; }
            else if (v > b2 || (v == b2 && k < c2)) { b2 = v; c2 = k; }
        }
        sIdx[0] = c1; sIdx[1] = c2;
    }
    __syncthreads();

    int wv = tid >> 6, lane = tid & 63;
    if (wv < 2) {                                  // wave kk handles row r = 2m+kk
        int r = m * 2 + wv;
        int b = m >> 3;
        const float* base = vfeat + (size_t)b * CDIM * NN2 + sIdx[wv];
        float v[4];
        float ss = 0.0f;
#pragma unroll
        for (int q = 0; q < 4; ++q) {
            int c = lane + 64 * q;
            v[q] = base[(size_t)c * NN2];
            ss += v[q] * v[q];
        }
#pragma unroll
        for (int o = 32; o > 0; o >>= 1) ss += __shfl_xor(ss, o, 64);
        float inv = 1.0f / fmaxf(sqrtf(ss), 1e-12f);
#pragma unroll
        for (int q = 0; q < 4; ++q) {
            int c = lane + 64 * q;
            float val = v[q] * inv;
            pos[r * CDIM + c] = val;
            int idx = (((c >> 5) * 8 + (r >> 4)) * 64 + ((r & 15) | (((c >> 3) & 3) << 4))) * 8 + (c & 7);
            posFrag[idx] = f2bf(val);
        }
    }
}

// ---------------- Kernel 2: MFMA tall-skinny GEMM + norm + exp + masked row-sum --
// Changes vs previous: (a) A-fragments loaded per-phase from L2-resident posFrag
// with static indices (frees ~48 VGPRs, removes runtime-indexed-array scratch
// hazard), (b) phase loop force-unrolled, (c) part written transposed (coalesced
// 512B store per block instead of 128 scattered 4B writes).
__global__ __launch_bounds__(512, 4) void neg_kernel(const float* __restrict__ vfeat,
                                                     const float* __restrict__ iou2d,
                                                     const unsigned short* __restrict__ posFrag,
                                                     float* __restrict__ part) {
    __shared__ unsigned short sB[2][2][4][64][8];   // [buf][s][ntile][slot][j]  16 KB
    __shared__ int   sIJ[64];
    __shared__ int   sMask[64];
    __shared__ float sNP[8][64];
    __shared__ float sInv[64];
    __shared__ float sNeg[RR];

    int tid = threadIdx.x;
    int bid = blockIdx.x;
    int b   = bid / BPB;
    int p0  = (bid - b * BPB) * 64;

    if (tid < RR) sNeg[tid] = 0.0f;
    if (tid < 64) {
        int p = p0 + tid;
        int i = (int)((257.0f - sqrtf(66049.0f - 8.0f * (float)p)) * 0.5f);
        if (i < 0) i = 0;
        while ((i + 1) * (257 - (i + 1)) / 2 <= p) ++i;
        while (i * (257 - i) / 2 > p) --i;
        int j = p - i * (257 - i) / 2 + i;
        int ij = i * NN + j;
        sIJ[tid] = ij;
        int mask = 0;
#pragma unroll
        for (int t = 0; t < 4; ++t) {
            float iv = iou2d[((size_t)(4 * b + t)) * NN2 + ij];
            mask |= (iv > NEGIOU) ? (1 << t) : 0;
        }
        sMask[tid] = mask;
    }

    int lane = tid & 63;
    int col  = tid & 63;
    int wv   = tid >> 6;                    // 0..7
    int rowgroup = wv >> 1;                 // 0..3 -> rows rowgroup*32
    int colgroup = wv & 1;                  // 0..1 -> cols colgroup*32

    const bf16x8* pf = (const bf16x8*)posFrag;

    __syncthreads();                        // sIJ/sMask ready

    const float* vcol = vfeat + (size_t)b * CDIM * NN2 + sIJ[col];

    f32x4 acc[2][2];
#pragma unroll
    for (int mt = 0; mt < 2; ++mt)
#pragma unroll
        for (int nt = 0; nt < 2; ++nt)
#pragma unroll
            for (int e = 0; e < 4; ++e) acc[mt][nt][e] = 0.0f;

    float nrm = 0.0f;
    float r[8];
#pragma unroll
    for (int j = 0; j < 8; ++j) r[j] = vcol[(size_t)(wv * 8 + j) * NN2];

    int s_loc = wv >> 2;
    int slot  = (col & 15) | ((wv & 3) << 4);
    int nt_w  = col >> 4;

#pragma unroll
    for (int ph = 0; ph < 4; ++ph) {
        // A-fragments for this phase: L2-hit broadcast loads, static indices.
        bf16x8 af[2][2];                    // [s][mt]
#pragma unroll
        for (int s = 0; s < 2; ++s)
#pragma unroll
            for (int mt = 0; mt < 2; ++mt)
                af[s][mt] = pf[((ph * 2 + s) * 8 + rowgroup * 2 + mt) * 64 + lane];

        union { bf16x8 v; unsigned u[4]; } pkd;
#pragma unroll
        for (int j = 0; j < 4; ++j)
            pkd.u[j] = (unsigned)f2bf(r[2 * j]) | ((unsigned)f2bf(r[2 * j + 1]) << 16);
#pragma unroll
        for (int j = 0; j < 8; ++j) nrm = fmaf(r[j], r[j], nrm);
        *(bf16x8*)&sB[ph & 1][s_loc][nt_w][slot][0] = pkd.v;
        __syncthreads();
        if (ph < 3) {
#pragma unroll
            for (int j = 0; j < 8; ++j)
                r[j] = vcol[(size_t)((ph + 1) * 64 + wv * 8 + j) * NN2];
        }
#pragma unroll
        for (int s = 0; s < 2; ++s)
#pragma unroll
            for (int ntl = 0; ntl < 2; ++ntl) {
                bf16x8 bfrag = *(const bf16x8*)&sB[ph & 1][s][colgroup * 2 + ntl][lane][0];
#pragma unroll
                for (int mt = 0; mt < 2; ++mt)
                    acc[mt][ntl] = __builtin_amdgcn_mfma_f32_16x16x32_bf16(
                        af[s][mt], bfrag, acc[mt][ntl], 0, 0, 0);
            }
    }

    sNP[wv][col] = nrm;
    __syncthreads();
    if (tid < 64) {
        float s = 0.0f;
        for (int t = 0; t < 8; ++t) s += sNP[t][tid];
        sInv[tid] = 10.0f / fmaxf(sqrtf(s), 1e-12f);   // 1/(T*norm), T=0.1
    }
    __syncthreads();

#pragma unroll
    for (int mt = 0; mt < 2; ++mt)
#pragma unroll
        for (int ntl = 0; ntl < 2; ++ntl)
#pragma unroll
            for (int reg = 0; reg < 4; ++reg) {
                int row = rowgroup * 32 + mt * 16 + ((lane >> 4) << 2) + reg;
                int cl  = colgroup * 32 + ntl * 16 + (lane & 15);
                float e = __expf(acc[mt][ntl][reg] * sInv[cl]);
                int excl = ((row >> 4) == b) & ((sMask[cl] >> ((row >> 2) & 3)) & 1);
                e = excl ? 0.0f : e;
#pragma unroll
                for (int off = 1; off < 16; off <<= 1) e += __shfl_xor(e, off, 64);
                if ((lane & 15) == 0) atomicAdd(&sNeg[row], e);
            }
    __syncthreads();
    if (tid < RR) part[(size_t)bid * RR + tid] = sNeg[tid];   // coalesced
}

// ---------------- Kernel 3: reduce per-block partials -> neg_sum[128] ------------
// Same per-thread summation order as before (t = tid, tid+256, ...), transposed
// addressing to match the coalesced part layout.
__global__ __launch_bounds__(256) void reduce_kernel(const float* __restrict__ part,
                                                     float* __restrict__ neg) {
    int r = blockIdx.x, tid = threadIdx.x;
    float s = 0.0f;
    for (int t = tid; t < NBLK; t += 256) s += part[(size_t)t * RR + r];
#pragma unroll
    for (int o = 32; o > 0; o >>= 1) s += __shfl_xor(s, o, 64);
    __shared__ float sw[4];
    if ((tid & 63) == 0) sw[tid >> 6] = s;
    __syncthreads();
    if (tid == 0) neg[r] = sw[0] + sw[1] + sw[2] + sw[3];
}

// ---------------- Kernel 4: 512 pair dots + log-sum-exp + mean -------------------
__global__ __launch_bounds__(256) void loss_kernel(const float* __restrict__ pos,
                                                   const float* __restrict__ neg,
                                                   float* __restrict__ out) {
    int tid = threadIdx.x;
    float local = 0.0f;
    for (int e = tid; e < 512; e += 256) {
        int s  = e >> 4;
        int aa = (e >> 2) & 3;
        int bb = e & 3;
        int rr = s * 4 + aa;
        int pp = s * 4 + bb;
        const float4* pr = (const float4*)(pos + rr * CDIM);
        const float4* pq = (const float4*)(pos + pp * CDIM);
        float dot = 0.0f;
        for (int c = 0; c < CDIM / 4; ++c) {
            float4 a = pr[c], bv = pq[c];
            dot += a.x * bv.x + a.y * bv.y + a.z * bv.z + a.w * bv.w;
        }
        float x = dot / TEMP;                  // MARGIN = 0
        local += logf(__expf(x) + neg[rr]) - x;
    }
#pragma unroll
    for (int o = 32; o > 0; o >>= 1) local += __shfl_xor(local, o, 64);
    __shared__ float sred[4];
    if ((tid & 63) == 0) sred[tid >> 6] = local;
    __syncthreads();
    if (tid == 0) out[0] = (sred[0] + sred[1] + sred[2] + sred[3]) / 512.0f;
}

extern "C" void kernel_launch(void* const* d_in, const int* in_sizes, int n_in,
                              void* d_out, int out_size, void* d_ws, size_t ws_size,
                              hipStream_t stream) {
    (void)in_sizes; (void)n_in; (void)out_size; (void)ws_size;
    const float* vfeat  = (const float*)d_in[0];
    const float* iou2d  = (const float*)d_in[4];
    const float* iou2ds = (const float*)d_in[5];

    float* ws = (float*)d_ws;
    float*          pos     = ws;                                   // 32768 f
    unsigned short* posFrag = (unsigned short*)(ws + 32768);        // 16384 f-equiv
    float*          part    = ws + 32768 + 16384;                   // 1032*128 f
    float*          neg     = part + (size_t)RR * NBLK;             // 128 f

    pos_kernel   <<<MM, 256, 0, stream>>>(iou2ds, vfeat, pos, posFrag);
    neg_kernel   <<<NBLK, 512, 0, stream>>>(vfeat, iou2d, posFrag, part);
    reduce_kernel<<<RR, 256, 0, stream>>>(part, neg);
    loss_kernel  <<<1, 256, 0, stream>>>(pos, neg, (float*)d_out);
}

// Round 2
// 255.887 us; speedup vs baseline: 1.0766x; 1.0766x over previous
//
#include <hip/hip_runtime.h>
#include <math.h>

#define NN    128
#define NN2   16384        // N*N
#define CDIM  256
#define BV    8
#define MM    64
#define RR    128          // M*K pos rows
#define PP    8256         // N*(N+1)/2
#define NBLK  1032         // 66048 / 64 cols per block
#define BPB   129          // blocks per video (8256/64)
#define TEMP  0.1f
#define NEGIOU 0.5f

typedef __attribute__((ext_vector_type(8))) short bf16x8;
typedef __attribute__((ext_vector_type(4))) float f32x4;

static __device__ __forceinline__ unsigned short f2bf(float x) {
    union { float f; unsigned u; } c; c.f = x;
    unsigned r = c.u + 0x7FFFu + ((c.u >> 16) & 1u);   // RNE
    return (unsigned short)(r >> 16);
}

// ---------------- Kernel 1a: partial top-2 per (moment, quarter) -----------------
// 256 blocks (64 moments x 4 quarters) so the 4 MB iou2ds scan stays BW-bound.
__global__ __launch_bounds__(256) void topk_part_kernel(const float* __restrict__ iou2ds,
                                                        float* __restrict__ pv,
                                                        int* __restrict__ pk) {
    int m = blockIdx.x, q = blockIdx.y, tid = threadIdx.x;
    const float* src = iou2ds + (size_t)m * NN2;
    float v1 = -1e30f, v2 = -1e30f;
    int k1 = 0x7fffffff, k2 = 0x7fffffff;
    int base = q * 4096;
#pragma unroll
    for (int i = 0; i < 16; ++i) {
        int k = base + tid + 256 * i;
        int r = k >> 7, c = k & 127;
        if (c < r) continue;                     // upper-triangular mask
        float v = src[k];
        if (v > v1 || (v == v1 && k < k1)) { v2 = v1; k2 = k1; v1 = v; k1 = k; }
        else if (v > v2 || (v == v2 && k < k2)) { v2 = v; k2 = k; }
    }
    __shared__ float sv[512];  __shared__ int sk[512];
    __shared__ float sv2[128]; __shared__ int sk2[128];
    sv[tid * 2] = v1; sv[tid * 2 + 1] = v2;
    sk[tid * 2] = k1; sk[tid * 2 + 1] = k2;
    __syncthreads();
    if (tid < 64) {
        float b1 = -1e30f, b2 = -1e30f; int c1 = 0x7fffffff, c2 = 0x7fffffff;
        for (int t = tid * 8; t < tid * 8 + 8; ++t) {
            float v = sv[t]; int k = sk[t];
            if (v > b1 || (v == b1 && k < c1)) { b2 = b1; c2 = c1; b1 = v; c1 = k; }
            else if (v > b2 || (v == b2 && k < c2)) { b2 = v; c2 = k; }
        }
        sv2[tid * 2] = b1; sv2[tid * 2 + 1] = b2;
        sk2[tid * 2] = c1; sk2[tid * 2 + 1] = c2;
    }
    __syncthreads();
    if (tid == 0) {
        float b1 = -1e30f, b2 = -1e30f; int c1 = 0x7fffffff, c2 = 0x7fffffff;
        for (int t = 0; t < 128; ++t) {
            float v = sv2[t]; int k = sk2[t];
            if (v > b1 || (v == b1 && k < c1)) { b2 = b1; c2 = c1; b1 = v; c1 = k; }
            else if (v > b2 || (v == b2 && k < c2)) { b2 = v; c2 = k; }
        }
        pv[(m * 4 + q) * 2] = b1; pv[(m * 4 + q) * 2 + 1] = b2;
        pk[(m * 4 + q) * 2] = c1; pk[(m * 4 + q) * 2 + 1] = c2;
    }
}

// ---------------- Kernel 2: merge partials, pos fp32 + pos bf16 frag layout ------
// posFrag layout: [s=k>>5][mt=r>>4][slot=(r&15)|(((k>>3)&3)<<4)][j=k&7]  (ushort)
__global__ __launch_bounds__(64) void posfeat_kernel(const float* __restrict__ vfeat,
                                                     const float* __restrict__ pv,
                                                     const int* __restrict__ pk,
                                                     float* __restrict__ pos,
                                                     unsigned short* __restrict__ posFrag) {
    int r = blockIdx.x, lane = threadIdx.x;
    int m = r >> 1, b = m >> 3, kk = r & 1;
    float b1 = -1e30f, b2 = -1e30f; int c1 = 0x7fffffff, c2 = 0x7fffffff;
    for (int t = 0; t < 8; ++t) {
        float v = pv[m * 8 + t]; int k = pk[m * 8 + t];
        if (v > b1 || (v == b1 && k < c1)) { b2 = b1; c2 = c1; b1 = v; c1 = k; }
        else if (v > b2 || (v == b2 && k < c2)) { b2 = v; c2 = k; }
    }
    int ij = kk ? c2 : c1;
    const float* base = vfeat + (size_t)b * CDIM * NN2 + ij;
    float v[4];
    float ss = 0.0f;
#pragma unroll
    for (int q = 0; q < 4; ++q) {
        int c = lane + 64 * q;
        v[q] = base[(size_t)c * NN2];
        ss += v[q] * v[q];
    }
#pragma unroll
    for (int o = 32; o > 0; o >>= 1) ss += __shfl_xor(ss, o, 64);
    float inv = 1.0f / fmaxf(sqrtf(ss), 1e-12f);
#pragma unroll
    for (int q = 0; q < 4; ++q) {
        int c = lane + 64 * q;
        float val = v[q] * inv;
        pos[r * CDIM + c] = val;
        int idx = (((c >> 5) * 8 + (r >> 4)) * 64 + ((r & 15) | (((c >> 3) & 3) << 4))) * 8 + (c & 7);
        posFrag[idx] = f2bf(val);
    }
}

// ---------------- Kernel 3: MFMA tall-skinny GEMM + norm + exp + masked row-sum --
// Round-0 structure (register-held afrag, one barrier per phase) with two safe
// changes: phase loop force-unrolled (static afrag/sB indices) and part written
// transposed (one coalesced 512B store per block instead of 128 scattered 4B).
__global__ __launch_bounds__(512, 4) void neg_kernel(const float* __restrict__ vfeat,
                                                     const float* __restrict__ iou2d,
                                                     const unsigned short* __restrict__ posFrag,
                                                     float* __restrict__ part) {
    __shared__ unsigned short sB[2][2][4][64][8];   // [buf][s][ntile][slot][j]  16 KB
    __shared__ int   sIJ[64];
    __shared__ int   sMask[64];
    __shared__ float sNP[8][64];
    __shared__ float sInv[64];
    __shared__ float sNeg[RR];

    int tid = threadIdx.x;
    int bid = blockIdx.x;
    int b   = bid / BPB;
    int p0  = (bid - b * BPB) * 64;

    if (tid < RR) sNeg[tid] = 0.0f;
    if (tid < 64) {
        int p = p0 + tid;
        int i = (int)((257.0f - sqrtf(66049.0f - 8.0f * (float)p)) * 0.5f);
        if (i < 0) i = 0;
        while ((i + 1) * (257 - (i + 1)) / 2 <= p) ++i;
        while (i * (257 - i) / 2 > p) --i;
        int j = p - i * (257 - i) / 2 + i;
        int ij = i * NN + j;
        sIJ[tid] = ij;
        int mask = 0;
#pragma unroll
        for (int t = 0; t < 4; ++t) {
            float iv = iou2d[((size_t)(4 * b + t)) * NN2 + ij];
            mask |= (iv > NEGIOU) ? (1 << t) : 0;
        }
        sMask[tid] = mask;
    }

    int lane = tid & 63;
    int col  = tid & 63;
    int wv   = tid >> 6;                    // 0..7
    int rowgroup = wv >> 1;                 // 0..3 -> rows rowgroup*32
    int colgroup = wv & 1;                  // 0..1 -> cols colgroup*32

    bf16x8 afrag[2][8];
    const bf16x8* pf = (const bf16x8*)posFrag;
#pragma unroll
    for (int mt = 0; mt < 2; ++mt)
#pragma unroll
        for (int s = 0; s < 8; ++s)
            afrag[mt][s] = pf[(s * 8 + rowgroup * 2 + mt) * 64 + lane];

    __syncthreads();                        // sIJ/sMask ready

    const float* vcol = vfeat + (size_t)b * CDIM * NN2 + sIJ[col];

    f32x4 acc[2][2];
#pragma unroll
    for (int mt = 0; mt < 2; ++mt)
#pragma unroll
        for (int nt = 0; nt < 2; ++nt)
#pragma unroll
            for (int e = 0; e < 4; ++e) acc[mt][nt][e] = 0.0f;

    float nrm = 0.0f;
    float r[8];
#pragma unroll
    for (int j = 0; j < 8; ++j) r[j] = vcol[(size_t)(wv * 8 + j) * NN2];

    int s_loc = wv >> 2;
    int slot  = (col & 15) | ((wv & 3) << 4);
    int nt_w  = col >> 4;

#pragma unroll
    for (int ph = 0; ph < 4; ++ph) {
        union { bf16x8 v; unsigned u[4]; } pkd;
#pragma unroll
        for (int j = 0; j < 4; ++j)
            pkd.u[j] = (unsigned)f2bf(r[2 * j]) | ((unsigned)f2bf(r[2 * j + 1]) << 16);
#pragma unroll
        for (int j = 0; j < 8; ++j) nrm = fmaf(r[j], r[j], nrm);
        *(bf16x8*)&sB[ph & 1][s_loc][nt_w][slot][0] = pkd.v;
        __syncthreads();
        if (ph < 3) {
#pragma unroll
            for (int j = 0; j < 8; ++j)
                r[j] = vcol[(size_t)((ph + 1) * 64 + wv * 8 + j) * NN2];
        }
#pragma unroll
        for (int s = 0; s < 2; ++s)
#pragma unroll
            for (int ntl = 0; ntl < 2; ++ntl) {
                bf16x8 bfrag = *(const bf16x8*)&sB[ph & 1][s][colgroup * 2 + ntl][lane][0];
#pragma unroll
                for (int mt = 0; mt < 2; ++mt)
                    acc[mt][ntl] = __builtin_amdgcn_mfma_f32_16x16x32_bf16(
                        afrag[mt][ph * 2 + s], bfrag, acc[mt][ntl], 0, 0, 0);
            }
    }

    sNP[wv][col] = nrm;
    __syncthreads();
    if (tid < 64) {
        float s = 0.0f;
        for (int t = 0; t < 8; ++t) s += sNP[t][tid];
        sInv[tid] = 10.0f / fmaxf(sqrtf(s), 1e-12f);   // 1/(T*norm), T=0.1
    }
    __syncthreads();

#pragma unroll
    for (int mt = 0; mt < 2; ++mt)
#pragma unroll
        for (int ntl = 0; ntl < 2; ++ntl)
#pragma unroll
            for (int reg = 0; reg < 4; ++reg) {
                int row = rowgroup * 32 + mt * 16 + ((lane >> 4) << 2) + reg;
                int cl  = colgroup * 32 + ntl * 16 + (lane & 15);
                float e = __expf(acc[mt][ntl][reg] * sInv[cl]);
                int excl = ((row >> 4) == b) & ((sMask[cl] >> ((row >> 2) & 3)) & 1);
                e = excl ? 0.0f : e;
#pragma unroll
                for (int off = 1; off < 16; off <<= 1) e += __shfl_xor(e, off, 64);
                if ((lane & 15) == 0) atomicAdd(&sNeg[row], e);
            }
    __syncthreads();
    if (tid < RR) part[(size_t)bid * RR + tid] = sNeg[tid];   // coalesced 512B store
}

// ---------------- Kernel 4: reduce per-block partials -> neg_sum[128] ------------
// Transposed addressing to match the coalesced part layout; same per-thread
// summation order (t ascending == bid ascending) -> bit-identical result.
__global__ __launch_bounds__(256) void reduce_kernel(const float* __restrict__ part,
                                                     float* __restrict__ neg) {
    int r = blockIdx.x, tid = threadIdx.x;
    float s = 0.0f;
    for (int t = tid; t < NBLK; t += 256) s += part[(size_t)t * RR + r];
#pragma unroll
    for (int o = 32; o > 0; o >>= 1) s += __shfl_xor(s, o, 64);
    __shared__ float sw[4];
    if ((tid & 63) == 0) sw[tid >> 6] = s;
    __syncthreads();
    if (tid == 0) neg[r] = sw[0] + sw[1] + sw[2] + sw[3];
}

// ---------------- Kernel 5: 512 pair dots + log-sum-exp + mean -------------------
__global__ __launch_bounds__(256) void loss_kernel(const float* __restrict__ pos,
                                                   const float* __restrict__ neg,
                                                   float* __restrict__ out) {
    int tid = threadIdx.x;
    float local = 0.0f;
    for (int e = tid; e < 512; e += 256) {
        int s  = e >> 4;
        int aa = (e >> 2) & 3;
        int bb = e & 3;
        int rr = s * 4 + aa;
        int pp = s * 4 + bb;
        const float4* pr = (const float4*)(pos + rr * CDIM);
        const float4* pq = (const float4*)(pos + pp * CDIM);
        float dot = 0.0f;
        for (int c = 0; c < CDIM / 4; ++c) {
            float4 a = pr[c], bv = pq[c];
            dot += a.x * bv.x + a.y * bv.y + a.z * bv.z + a.w * bv.w;
        }
        float x = dot / TEMP;                  // MARGIN = 0
        local += logf(__expf(x) + neg[rr]) - x;
    }
#pragma unroll
    for (int o = 32; o > 0; o >>= 1) local += __shfl_xor(local, o, 64);
    __shared__ float sred[4];
    if ((tid & 63) == 0) sred[tid >> 6] = local;
    __syncthreads();
    if (tid == 0) out[0] = (sred[0] + sred[1] + sred[2] + sred[3]) / 512.0f;
}

extern "C" void kernel_launch(void* const* d_in, const int* in_sizes, int n_in,
                              void* d_out, int out_size, void* d_ws, size_t ws_size,
                              hipStream_t stream) {
    (void)in_sizes; (void)n_in; (void)out_size; (void)ws_size;
    const float* vfeat  = (const float*)d_in[0];
    const float* iou2d  = (const float*)d_in[4];
    const float* iou2ds = (const float*)d_in[5];

    float* ws = (float*)d_ws;
    float*          pos     = ws;                                   // 32768 f
    unsigned short* posFrag = (unsigned short*)(ws + 32768);        // 16384 f-equiv
    float*          pv      = ws + 32768 + 16384;                   // 512 f
    int*            pk      = (int*)(pv + 512);                     // 512 i
    float*          part    = pv + 1024;                            // 1032*128 f
    float*          neg     = part + (size_t)RR * NBLK;             // 128 f

    topk_part_kernel<<<dim3(MM, 4), 256, 0, stream>>>(iou2ds, pv, pk);
    posfeat_kernel  <<<RR, 64, 0, stream>>>(vfeat, pv, pk, pos, posFrag);
    neg_kernel      <<<NBLK, 512, 0, stream>>>(vfeat, iou2d, posFrag, part);
    reduce_kernel   <<<RR, 256, 0, stream>>>(part, neg);
    loss_kernel     <<<1, 256, 0, stream>>>(pos, neg, (float*)d_out);
}